// Round 6
// baseline (270.305 us; speedup 1.0000x reference)
//
#include <hip/hip_runtime.h>
#include <hip/hip_cooperative_groups.h>
#include <math.h>

namespace cg = cooperative_groups;

#define NHID 512
#define T_K  256
#define T_Q  128
#define BB   8

// tanh(x) = 1 - 2/(exp2(C*x)+1), C = 2*log2(e)
constexpr float C2L2E = 2.8853900817779268f;
constexpr float L2E   = 1.4426950408889634f;

__device__ __forceinline__ float fexp2(float x) { return __builtin_amdgcn_exp2f(x); }
__device__ __forceinline__ float frcp(float x)  { return __builtin_amdgcn_rcpf(x); }

typedef __attribute__((ext_vector_type(8))) short bf16x8;
typedef __attribute__((ext_vector_type(4))) float f32x4;

__device__ __forceinline__ unsigned short f2bf(float x) {
    unsigned u = __builtin_bit_cast(unsigned, x);
    unsigned r = (u + 0x7FFFu + ((u >> 16) & 1u)) >> 16;
    return (unsigned short)r;
}
__device__ __forceinline__ float bf2f(unsigned short h) {
    unsigned u = ((unsigned)h) << 16;
    return __builtin_bit_cast(float, u);
}

// Shared-memory union across phases (max 36864 B -> 2 blocks/CU = 72 KB)
union MegaShared {
    struct { unsigned short Ah[4096], Al[4096], Bh[4096], Bl[4096]; } pj; // 32 KB
    struct { float tile[64][65]; } cv;                                    // 16.6 KB
    struct { float kb[2][32][66]; float qb[2][8][66]; float w2s[512]; } sc; // 23.1 KB
    struct { float p[4][256]; float pacc[4][4][512]; } sv;                // 36 KB
};

// ===========================================================================
// MEGA KERNEL: conv -> proj -> score -> softmax+antvec with grid syncs.
// ===========================================================================
__global__ __launch_bounds__(256, 2) void mega_kernel(
    const float* __restrict__ qry, const float* __restrict__ ckey,
    const int* __restrict__ mask, const float* __restrict__ W1,
    const float* __restrict__ b1, const float* __restrict__ W2,
    const float* __restrict__ b2,
    unsigned short* __restrict__ bt_hi, unsigned short* __restrict__ bt_lo,
    float* __restrict__ ek, float* __restrict__ eq, float* __restrict__ sc_ws,
    float* __restrict__ out_prob, float* __restrict__ out_ant)
{
    cg::grid_group grid = cg::this_grid();
    __shared__ MegaShared sh;
    const int t    = threadIdx.x;
    const int lane = t & 63;
    const int wave = __builtin_amdgcn_readfirstlane(t >> 6);
    const unsigned nb = gridDim.x;

    // ---------------- Phase 0: W1 transpose + split-bf16 (128 units) -------
    for (unsigned u = blockIdx.x; u < 128; u += nb) {
        const int kt = u & 15, nt = u >> 4;
        const int r  = t >> 2;
        const int c0 = (t & 3) * 16;
        const float* src = W1 + (size_t)(kt * 64 + r) * 512 + nt * 64 + c0;
        #pragma unroll
        for (int j = 0; j < 4; ++j) {
            const float4 v = *(const float4*)&src[j * 4];
            sh.cv.tile[r][c0 + j * 4 + 0] = v.x; sh.cv.tile[r][c0 + j * 4 + 1] = v.y;
            sh.cv.tile[r][c0 + j * 4 + 2] = v.z; sh.cv.tile[r][c0 + j * 4 + 3] = v.w;
        }
        __syncthreads();
        const size_t dst = (size_t)((kt >> 3) * 512 + nt * 64 + r) * 512
                         + (size_t)((kt & 7) * 64 + c0);
        #pragma unroll
        for (int j4 = 0; j4 < 4; ++j4) {
            ushort4 h, l;
            #pragma unroll
            for (int e = 0; e < 4; ++e) {
                const float x = sh.cv.tile[c0 + j4 * 4 + e][r];
                const unsigned short hb = f2bf(x);
                ((unsigned short*)&h)[e] = hb;
                ((unsigned short*)&l)[e] = f2bf(x - bf2f(hb));
            }
            *(ushort4*)&bt_hi[dst + j4 * 4] = h;
            *(ushort4*)&bt_lo[dst + j4 * 4] = l;
        }
        __syncthreads();
    }
    grid.sync();

    // ---------------- Phase 1: proj GEMM (384 units) -----------------------
    for (unsigned u = blockIdx.x; u < 384; u += nb) {
        const int row0 = (int)(u % 48) * 64;
        const int col0 = (int)(u / 48) * 64;
        const bool isK = row0 < 2048;
        const int bhalf = isK ? 0 : 512;

        const int wm = (wave & 1) * 32;
        const int wn = (wave >> 1) * 32;
        f32x4 acc[2][2] = {};

        const int sr = t >> 2;
        const int sc = (t & 3) * 16;
        const float* gA = (isK ? ckey + (size_t)(row0 + sr) * 512
                               : qry  + (size_t)(row0 - 2048 + sr) * 512) + sc;
        const unsigned short* gBh = bt_hi + (size_t)(bhalf + col0 + sr) * 512 + sc;
        const unsigned short* gBl = bt_lo + (size_t)(bhalf + col0 + sr) * 512 + sc;
        const int c0c = sc >> 3;
        const int sw0 = ((c0c + 0) ^ (sr & 7)) * 8;
        const int sw1 = ((c0c + 1) ^ (sr & 7)) * 8;
        const int quad = lane >> 4, fr = lane & 15;

        for (int k0 = 0; k0 < 512; k0 += 64) {
            __syncthreads();
            {
                float fa[16];
                *(float4*)&fa[0]  = *(const float4*)&gA[k0 + 0];
                *(float4*)&fa[4]  = *(const float4*)&gA[k0 + 4];
                *(float4*)&fa[8]  = *(const float4*)&gA[k0 + 8];
                *(float4*)&fa[12] = *(const float4*)&gA[k0 + 12];
                union { uint4 v; unsigned short s[8]; } h0, l0, h1, l1;
                #pragma unroll
                for (int e = 0; e < 8; ++e) {
                    const unsigned short hb = f2bf(fa[e]);
                    h0.s[e] = hb; l0.s[e] = f2bf(fa[e] - bf2f(hb));
                }
                #pragma unroll
                for (int e = 0; e < 8; ++e) {
                    const unsigned short hb = f2bf(fa[8 + e]);
                    h1.s[e] = hb; l1.s[e] = f2bf(fa[8 + e] - bf2f(hb));
                }
                *(uint4*)&sh.pj.Ah[sr * 64 + sw0] = h0.v; *(uint4*)&sh.pj.Ah[sr * 64 + sw1] = h1.v;
                *(uint4*)&sh.pj.Al[sr * 64 + sw0] = l0.v; *(uint4*)&sh.pj.Al[sr * 64 + sw1] = l1.v;
                uint4 v0, v1;
                v0 = *(const uint4*)&gBh[k0];     v1 = *(const uint4*)&gBh[k0 + 8];
                *(uint4*)&sh.pj.Bh[sr * 64 + sw0] = v0; *(uint4*)&sh.pj.Bh[sr * 64 + sw1] = v1;
                v0 = *(const uint4*)&gBl[k0];     v1 = *(const uint4*)&gBl[k0 + 8];
                *(uint4*)&sh.pj.Bl[sr * 64 + sw0] = v0; *(uint4*)&sh.pj.Bl[sr * 64 + sw1] = v1;
            }
            __syncthreads();
            #pragma unroll
            for (int ks = 0; ks < 2; ++ks) {
                const int cchunk = ks * 4 + quad;
                bf16x8 afh[2], afl[2], bfh[2], bfl[2];
                #pragma unroll
                for (int mt = 0; mt < 2; ++mt) {
                    const int m = wm + mt * 16 + fr;
                    afh[mt] = *(const bf16x8*)&sh.pj.Ah[m * 64 + ((cchunk ^ (m & 7)) * 8)];
                    afl[mt] = *(const bf16x8*)&sh.pj.Al[m * 64 + ((cchunk ^ (m & 7)) * 8)];
                }
                #pragma unroll
                for (int nt = 0; nt < 2; ++nt) {
                    const int n = wn + nt * 16 + fr;
                    bfh[nt] = *(const bf16x8*)&sh.pj.Bh[n * 64 + ((cchunk ^ (n & 7)) * 8)];
                    bfl[nt] = *(const bf16x8*)&sh.pj.Bl[n * 64 + ((cchunk ^ (n & 7)) * 8)];
                }
                #pragma unroll
                for (int mt = 0; mt < 2; ++mt)
                    #pragma unroll
                    for (int nt = 0; nt < 2; ++nt) {
                        acc[mt][nt] = __builtin_amdgcn_mfma_f32_16x16x32_bf16(afh[mt], bfh[nt], acc[mt][nt], 0, 0, 0);
                        acc[mt][nt] = __builtin_amdgcn_mfma_f32_16x16x32_bf16(afh[mt], bfl[nt], acc[mt][nt], 0, 0, 0);
                        acc[mt][nt] = __builtin_amdgcn_mfma_f32_16x16x32_bf16(afl[mt], bfh[nt], acc[mt][nt], 0, 0, 0);
                    }
            }
        }
        #pragma unroll
        for (int nt = 0; nt < 2; ++nt) {
            const int colg = col0 + wn + nt * 16 + fr;
            const float b1v = b1[colg];
            #pragma unroll
            for (int mt = 0; mt < 2; ++mt) {
                #pragma unroll
                for (int i = 0; i < 4; ++i) {
                    const int rowg = row0 + wm + mt * 16 + quad * 4 + i;
                    const float v = acc[mt][nt][i];
                    if (isK) ek[(size_t)rowg * 512 + colg] = fexp2((v + b1v) * C2L2E);
                    else     eq[(size_t)(rowg - 2048) * 512 + colg] = fexp2(v * C2L2E);
                }
            }
        }
        __syncthreads();
    }
    grid.sync();

    // ---------------- Phase 2: score (1024 units) --------------------------
    {
        const float4 wA = *(const float4*)&W2[lane * 4];
        const float4 wB = *(const float4*)&W2[256 + lane * 4];
        float s2 = wA.x + wA.y + wA.z + wA.w + wB.x + wB.y + wB.z + wB.w;
        #pragma unroll
        for (int m = 32; m; m >>= 1) s2 += __shfl_xor(s2, m, 64);
        const float base = s2 + b2[0];

        *(float2*)&sh.sc.w2s[t * 2] = *(const float2*)&W2[t * 2];
        __syncthreads();

        const int kk = lane >> 1;
        const int p  = lane & 1;
        const int srk = t >> 3;            // 0..31
        const int sck = (t & 7) * 8;       // 0..56
        const int srq = t >> 5;            // 0..7
        const int scq = (t & 31) * 2;      // 0..62

        for (unsigned u = blockIdx.x; u < 1024; u += nb) {
            const int k0 = (int)(u & 7) * 32;
            const int q0 = (int)((u >> 3) & 15) * 8;
            const int b  = (int)(u >> 7);

            const float* ek_src = ek + ((size_t)(k0 + srk) * 8 + b) * 512 + sck;
            const float* eq_src = eq + ((size_t)(q0 + srq) * 8 + b) * 512 + scq;

            float4 pk0 = *(const float4*)&ek_src[0];
            float4 pk1 = *(const float4*)&ek_src[4];
            float2 pq0 = *(const float2*)&eq_src[0];

            *(float2*)&sh.sc.kb[0][srk][sck + 0] = {pk0.x, pk0.y};
            *(float2*)&sh.sc.kb[0][srk][sck + 2] = {pk0.z, pk0.w};
            *(float2*)&sh.sc.kb[0][srk][sck + 4] = {pk1.x, pk1.y};
            *(float2*)&sh.sc.kb[0][srk][sck + 6] = {pk1.z, pk1.w};
            *(float2*)&sh.sc.qb[0][srq][scq] = pq0;
            __syncthreads();

            float racc[2] = {0.f, 0.f};
            for (int chunk = 0; chunk < 8; ++chunk) {
                const int buf = chunk & 1;
                const int hc = chunk * 64;
                if (chunk < 7) {
                    pk0 = *(const float4*)&ek_src[hc + 64];
                    pk1 = *(const float4*)&ek_src[hc + 68];
                    pq0 = *(const float2*)&eq_src[hc + 64];
                }
                #pragma unroll
                for (int s = 0; s < 16; ++s) {
                    const float2 e01 = *(const float2*)&sh.sc.kb[buf][kk][4 * s + 2 * p];
                    const float2 w01 = *(const float2*)&sh.sc.w2s[hc + 4 * s + 2 * p];
                    const float wsum = w01.x + w01.y;
                    #pragma unroll
                    for (int qi = 0; qi < 2; ++qi) {
                        const float2 g01 = *(const float2*)&sh.sc.qb[buf][wave * 2 + qi][4 * s + 2 * p];
                        const float t0 = e01.x * g01.x;
                        const float t1 = e01.y * g01.y;
                        const float a   = fmaf(t0, t1, t0);
                        const float bb1 = t1 + 1.0f;
                        const float den = a + bb1;
                        const float num = fmaf(w01.x, t1, fmaf(w01.y, t0, wsum));
                        racc[qi] = fmaf(num, frcp(den), racc[qi]);
                    }
                }
                __syncthreads();
                if (chunk < 7) {
                    const int nxt = buf ^ 1;
                    *(float2*)&sh.sc.kb[nxt][srk][sck + 0] = {pk0.x, pk0.y};
                    *(float2*)&sh.sc.kb[nxt][srk][sck + 2] = {pk0.z, pk0.w};
                    *(float2*)&sh.sc.kb[nxt][srk][sck + 4] = {pk1.x, pk1.y};
                    *(float2*)&sh.sc.kb[nxt][srk][sck + 6] = {pk1.z, pk1.w};
                    *(float2*)&sh.sc.qb[nxt][srq][scq] = pq0;
                }
                __syncthreads();
            }

            const int kglob = k0 + kk;
            const int msk = mask[kglob * 8 + b];
            #pragma unroll
            for (int qi = 0; qi < 2; ++qi) {
                float r = racc[qi] + __shfl_xor(racc[qi], 1, 64);
                float scv = base - 2.0f * r;
                if (msk) scv = -INFINITY;
                if (p == 0)
                    sc_ws[((size_t)(q0 + wave * 2 + qi) * 8 + b) * 256 + kglob] = scv;
            }
        }
    }
    grid.sync();

    // ---------------- Phase 3: softmax + antvec (256 units) ----------------
    for (unsigned u = blockIdx.x; u < 256; u += nb) {
        const int qt = (int)(u >> 3);
        const int b  = (int)(u & 7);
        const int q  = qt * 4 + wave;
        const int qb_idx = q * 8 + b;

        float4 s4 = *(const float4*)&sc_ws[(size_t)qb_idx * 256 + lane * 4];
        float m = fmaxf(fmaxf(s4.x, s4.y), fmaxf(s4.z, s4.w));
        #pragma unroll
        for (int d = 32; d; d >>= 1) m = fmaxf(m, __shfl_xor(m, d, 64));

        float4 pv;
        pv.x = fexp2((s4.x - m) * L2E);
        pv.y = fexp2((s4.y - m) * L2E);
        pv.z = fexp2((s4.z - m) * L2E);
        pv.w = fexp2((s4.w - m) * L2E);
        float sum = pv.x + pv.y + pv.z + pv.w;
        #pragma unroll
        for (int d = 32; d; d >>= 1) sum += __shfl_xor(sum, d, 64);
        const float inv = frcp(sum);
        pv.x *= inv; pv.y *= inv; pv.z *= inv; pv.w *= inv;

        *(float4*)&sh.sv.p[wave][lane * 4] = pv;
        const int kbase = lane * 4;
        out_prob[(size_t)(kbase + 0) * 1024 + qb_idx] = pv.x;
        out_prob[(size_t)(kbase + 1) * 1024 + qb_idx] = pv.y;
        out_prob[(size_t)(kbase + 2) * 1024 + qb_idx] = pv.z;
        out_prob[(size_t)(kbase + 3) * 1024 + qb_idx] = pv.w;
        __syncthreads();

        const int h0 = lane * 8;
        float4 accL[4] = {}, accH[4] = {};
        const int kstart = wave * 64;
        #pragma unroll 4
        for (int ki = 0; ki < 64; ++ki) {
            const int k = kstart + ki;
            const float* ckp = &ckey[((size_t)k * 8 + b) * 512 + h0];
            const float4 c0 = *(const float4*)&ckp[0];
            const float4 c1 = *(const float4*)&ckp[4];
            #pragma unroll
            for (int qi = 0; qi < 4; ++qi) {
                const float pq = sh.sv.p[qi][k];
                accL[qi].x = fmaf(pq, c0.x, accL[qi].x);
                accL[qi].y = fmaf(pq, c0.y, accL[qi].y);
                accL[qi].z = fmaf(pq, c0.z, accL[qi].z);
                accL[qi].w = fmaf(pq, c0.w, accL[qi].w);
                accH[qi].x = fmaf(pq, c1.x, accH[qi].x);
                accH[qi].y = fmaf(pq, c1.y, accH[qi].y);
                accH[qi].z = fmaf(pq, c1.z, accH[qi].z);
                accH[qi].w = fmaf(pq, c1.w, accH[qi].w);
            }
        }
        #pragma unroll
        for (int qi = 0; qi < 4; ++qi) {
            *(float4*)&sh.sv.pacc[wave][qi][h0 + 0] = accL[qi];
            *(float4*)&sh.sv.pacc[wave][qi][h0 + 4] = accH[qi];
        }
        __syncthreads();

        const int h2 = t * 2;
        #pragma unroll
        for (int qi = 0; qi < 4; ++qi) {
            float2 r0 = *(const float2*)&sh.sv.pacc[0][qi][h2];
            float2 r1 = *(const float2*)&sh.sv.pacc[1][qi][h2];
            float2 r2 = *(const float2*)&sh.sv.pacc[2][qi][h2];
            float2 r3 = *(const float2*)&sh.sv.pacc[3][qi][h2];
            float2 r;
            r.x = (r0.x + r1.x) + (r2.x + r3.x);
            r.y = (r0.y + r1.y) + (r2.y + r3.y);
            *(float2*)&out_ant[((size_t)(qt * 4 + qi) * 8 + b) * 512 + h2] = r;
        }
        __syncthreads();
    }
}

// ===========================================================================
// FALLBACK PATH (R5 kernels) — used only if cooperative launch fails.
// ===========================================================================
__global__ __launch_bounds__(256) void convert_w1_kernel(
    const float* __restrict__ W1,
    unsigned short* __restrict__ bt_hi, unsigned short* __restrict__ bt_lo)
{
    const int tb = blockIdx.x;
    const int kt = tb & 15;
    const int nt = tb >> 4;
    __shared__ float tile[64][65];
    const int t  = threadIdx.x;
    const int r  = t >> 2;
    const int c0 = (t & 3) * 16;
    const float* src = W1 + (size_t)(kt * 64 + r) * 512 + nt * 64 + c0;
    #pragma unroll
    for (int j = 0; j < 4; ++j) {
        const float4 v = *(const float4*)&src[j * 4];
        tile[r][c0 + j * 4 + 0] = v.x; tile[r][c0 + j * 4 + 1] = v.y;
        tile[r][c0 + j * 4 + 2] = v.z; tile[r][c0 + j * 4 + 3] = v.w;
    }
    __syncthreads();
    const size_t dst = (size_t)((kt >> 3) * 512 + nt * 64 + r) * 512
                     + (size_t)((kt & 7) * 64 + c0);
    #pragma unroll
    for (int j4 = 0; j4 < 4; ++j4) {
        ushort4 h, l;
        #pragma unroll
        for (int e = 0; e < 4; ++e) {
            const float x = tile[c0 + j4 * 4 + e][r];
            const unsigned short hb = f2bf(x);
            ((unsigned short*)&h)[e] = hb;
            ((unsigned short*)&l)[e] = f2bf(x - bf2f(hb));
        }
        *(ushort4*)&bt_hi[dst + j4 * 4] = h;
        *(ushort4*)&bt_lo[dst + j4 * 4] = l;
    }
}

__global__ __launch_bounds__(256) void proj_kernel(
    const float* __restrict__ qry, const float* __restrict__ ckey,
    const unsigned short* __restrict__ bt_hi, const unsigned short* __restrict__ bt_lo,
    const float* __restrict__ b1,
    float* __restrict__ ek, float* __restrict__ eq)
{
    const int row0 = blockIdx.x * 64;
    const int col0 = blockIdx.y * 64;
    const bool isK = row0 < 2048;
    const int bhalf = isK ? 0 : 512;

    __shared__ __align__(16) unsigned short As_h[64 * 64];
    __shared__ __align__(16) unsigned short As_l[64 * 64];
    __shared__ __align__(16) unsigned short Bs_h[64 * 64];
    __shared__ __align__(16) unsigned short Bs_l[64 * 64];

    const int t    = threadIdx.x;
    const int wave = t >> 6;
    const int lane = t & 63;
    const int wm = (wave & 1) * 32;
    const int wn = (wave >> 1) * 32;

    f32x4 acc[2][2] = {};

    const int sr = t >> 2;
    const int sc = (t & 3) * 16;
    const float* gA = (isK ? ckey + (size_t)(row0 + sr) * 512
                           : qry  + (size_t)(row0 - 2048 + sr) * 512) + sc;
    const unsigned short* gBh = bt_hi + (size_t)(bhalf + col0 + sr) * 512 + sc;
    const unsigned short* gBl = bt_lo + (size_t)(bhalf + col0 + sr) * 512 + sc;
    const int c0c = sc >> 3;
    const int sw0 = ((c0c + 0) ^ (sr & 7)) * 8;
    const int sw1 = ((c0c + 1) ^ (sr & 7)) * 8;

    const int quad = lane >> 4, fr = lane & 15;

    for (int k0 = 0; k0 < 512; k0 += 64) {
        __syncthreads();
        {
            float fa[16];
            *(float4*)&fa[0]  = *(const float4*)&gA[k0 + 0];
            *(float4*)&fa[4]  = *(const float4*)&gA[k0 + 4];
            *(float4*)&fa[8]  = *(const float4*)&gA[k0 + 8];
            *(float4*)&fa[12] = *(const float4*)&gA[k0 + 12];
            union { uint4 v; unsigned short s[8]; } h0, l0, h1, l1;
            #pragma unroll
            for (int e = 0; e < 8; ++e) {
                const unsigned short hb = f2bf(fa[e]);
                h0.s[e] = hb; l0.s[e] = f2bf(fa[e] - bf2f(hb));
            }
            #pragma unroll
            for (int e = 0; e < 8; ++e) {
                const unsigned short hb = f2bf(fa[8 + e]);
                h1.s[e] = hb; l1.s[e] = f2bf(fa[8 + e] - bf2f(hb));
            }
            *(uint4*)&As_h[sr * 64 + sw0] = h0.v; *(uint4*)&As_h[sr * 64 + sw1] = h1.v;
            *(uint4*)&As_l[sr * 64 + sw0] = l0.v; *(uint4*)&As_l[sr * 64 + sw1] = l1.v;
            uint4 v0, v1;
            v0 = *(const uint4*)&gBh[k0];     v1 = *(const uint4*)&gBh[k0 + 8];
            *(uint4*)&Bs_h[sr * 64 + sw0] = v0; *(uint4*)&Bs_h[sr * 64 + sw1] = v1;
            v0 = *(const uint4*)&gBl[k0];     v1 = *(const uint4*)&gBl[k0 + 8];
            *(uint4*)&Bs_l[sr * 64 + sw0] = v0; *(uint4*)&Bs_l[sr * 64 + sw1] = v1;
        }
        __syncthreads();
        #pragma unroll
        for (int ks = 0; ks < 2; ++ks) {
            const int cchunk = ks * 4 + quad;
            bf16x8 afh[2], afl[2], bfh[2], bfl[2];
            #pragma unroll
            for (int mt = 0; mt < 2; ++mt) {
                const int m = wm + mt * 16 + fr;
                afh[mt] = *(const bf16x8*)&As_h[m * 64 + ((cchunk ^ (m & 7)) * 8)];
                afl[mt] = *(const bf16x8*)&As_l[m * 64 + ((cchunk ^ (m & 7)) * 8)];
            }
            #pragma unroll
            for (int nt = 0; nt < 2; ++nt) {
                const int n = wn + nt * 16 + fr;
                bfh[nt] = *(const bf16x8*)&Bs_h[n * 64 + ((cchunk ^ (n & 7)) * 8)];
                bfl[nt] = *(const bf16x8*)&Bs_l[n * 64 + ((cchunk ^ (n & 7)) * 8)];
            }
            #pragma unroll
            for (int mt = 0; mt < 2; ++mt)
                #pragma unroll
                for (int nt = 0; nt < 2; ++nt) {
                    acc[mt][nt] = __builtin_amdgcn_mfma_f32_16x16x32_bf16(afh[mt], bfh[nt], acc[mt][nt], 0, 0, 0);
                    acc[mt][nt] = __builtin_amdgcn_mfma_f32_16x16x32_bf16(afh[mt], bfl[nt], acc[mt][nt], 0, 0, 0);
                    acc[mt][nt] = __builtin_amdgcn_mfma_f32_16x16x32_bf16(afl[mt], bfh[nt], acc[mt][nt], 0, 0, 0);
                }
        }
    }

    #pragma unroll
    for (int nt = 0; nt < 2; ++nt) {
        const int colg = col0 + wn + nt * 16 + fr;
        const float b1v = b1[colg];
        #pragma unroll
        for (int mt = 0; mt < 2; ++mt) {
            #pragma unroll
            for (int i = 0; i < 4; ++i) {
                const int rowg = row0 + wm + mt * 16 + quad * 4 + i;
                const float v = acc[mt][nt][i];
                if (isK) ek[(size_t)rowg * 512 + colg] = fexp2((v + b1v) * C2L2E);
                else     eq[(size_t)(rowg - 2048) * 512 + colg] = fexp2(v * C2L2E);
            }
        }
    }
}

__global__ __launch_bounds__(256) void score_kernel(
    const float* __restrict__ ek, const float* __restrict__ eq,
    const float* __restrict__ W2, const float* __restrict__ b2,
    const int* __restrict__ mask, float* __restrict__ score)
{
    const int t    = threadIdx.x;
    const int wave = __builtin_amdgcn_readfirstlane(t >> 6);
    const int lane = t & 63;
    const int kk = lane >> 1;
    const int p  = lane & 1;
    const int k0 = blockIdx.x * 32;
    const int q0 = blockIdx.y * 8;
    const int b  = blockIdx.z;

    __shared__ float kb[2][32][66];
    __shared__ float qb[2][8][66];
    __shared__ float w2s[512];

    *(float2*)&w2s[t * 2] = *(const float2*)&W2[t * 2];

    const float4 wA = *(const float4*)&W2[lane * 4];
    const float4 wB = *(const float4*)&W2[256 + lane * 4];
    float s2 = wA.x + wA.y + wA.z + wA.w + wB.x + wB.y + wB.z + wB.w;
    #pragma unroll
    for (int m = 32; m; m >>= 1) s2 += __shfl_xor(s2, m, 64);
    const float base = s2 + b2[0];

    const int srk = t >> 3;
    const int sck = (t & 7) * 8;
    const float* ek_src = ek + ((size_t)(k0 + srk) * 8 + b) * 512 + sck;
    const int srq = t >> 5;
    const int scq = (t & 31) * 2;
    const float* eq_src = eq + ((size_t)(q0 + srq) * 8 + b) * 512 + scq;

    float4 pk0 = *(const float4*)&ek_src[0];
    float4 pk1 = *(const float4*)&ek_src[4];
    float2 pq0 = *(const float2*)&eq_src[0];

    *(float2*)&kb[0][srk][sck + 0] = {pk0.x, pk0.y};
    *(float2*)&kb[0][srk][sck + 2] = {pk0.z, pk0.w};
    *(float2*)&kb[0][srk][sck + 4] = {pk1.x, pk1.y};
    *(float2*)&kb[0][srk][sck + 6] = {pk1.z, pk1.w};
    *(float2*)&qb[0][srq][scq] = pq0;
    __syncthreads();

    float racc[2] = {0.f, 0.f};

    for (int chunk = 0; chunk < 8; ++chunk) {
        const int buf = chunk & 1;
        const int hc = chunk * 64;
        if (chunk < 7) {
            pk0 = *(const float4*)&ek_src[hc + 64];
            pk1 = *(const float4*)&ek_src[hc + 68];
            pq0 = *(const float2*)&eq_src[hc + 64];
        }
        #pragma unroll
        for (int s = 0; s < 16; ++s) {
            const float2 e01 = *(const float2*)&kb[buf][kk][4 * s + 2 * p];
            const float2 w01 = *(const float2*)&w2s[hc + 4 * s + 2 * p];
            const float wsum = w01.x + w01.y;
            #pragma unroll
            for (int qi = 0; qi < 2; ++qi) {
                const float2 g01 = *(const float2*)&qb[buf][wave * 2 + qi][4 * s + 2 * p];
                const float t0 = e01.x * g01.x;
                const float t1 = e01.y * g01.y;
                const float a   = fmaf(t0, t1, t0);
                const float bb1 = t1 + 1.0f;
                const float den = a + bb1;
                const float num = fmaf(w01.x, t1, fmaf(w01.y, t0, wsum));
                racc[qi] = fmaf(num, frcp(den), racc[qi]);
            }
        }
        __syncthreads();
        if (chunk < 7) {
            const int nxt = buf ^ 1;
            *(float2*)&kb[nxt][srk][sck + 0] = {pk0.x, pk0.y};
            *(float2*)&kb[nxt][srk][sck + 2] = {pk0.z, pk0.w};
            *(float2*)&kb[nxt][srk][sck + 4] = {pk1.x, pk1.y};
            *(float2*)&kb[nxt][srk][sck + 6] = {pk1.z, pk1.w};
            *(float2*)&qb[nxt][srq][scq] = pq0;
        }
        __syncthreads();
    }

    const int kglob = k0 + kk;
    const int msk = mask[kglob * 8 + b];
    #pragma unroll
    for (int qi = 0; qi < 2; ++qi) {
        float r = racc[qi] + __shfl_xor(racc[qi], 1, 64);
        float sc = base - 2.0f * r;
        if (msk) sc = -INFINITY;
        if (p == 0)
            score[((size_t)(q0 + wave * 2 + qi) * 8 + b) * 256 + kglob] = sc;
    }
}

__global__ __launch_bounds__(256) void smav_kernel(
    const float* __restrict__ score, const float* __restrict__ ckey,
    float* __restrict__ prob_out, float* __restrict__ out_ant)
{
    const int qt = blockIdx.x;
    const int b  = blockIdx.y;
    const int t  = threadIdx.x;
    const int wave = __builtin_amdgcn_readfirstlane(t >> 6);
    const int lane = t & 63;
    const int q  = qt * 4 + wave;
    const int qb_idx = q * 8 + b;

    __shared__ float p_lds[4][256];
    __shared__ float pacc[4][4][512];

    float4 s4 = *(const float4*)&score[(size_t)qb_idx * 256 + lane * 4];
    float m = fmaxf(fmaxf(s4.x, s4.y), fmaxf(s4.z, s4.w));
    #pragma unroll
    for (int d = 32; d; d >>= 1) m = fmaxf(m, __shfl_xor(m, d, 64));

    float4 pv;
    pv.x = fexp2((s4.x - m) * L2E);
    pv.y = fexp2((s4.y - m) * L2E);
    pv.z = fexp2((s4.z - m) * L2E);
    pv.w = fexp2((s4.w - m) * L2E);
    float sum = pv.x + pv.y + pv.z + pv.w;
    #pragma unroll
    for (int d = 32; d; d >>= 1) sum += __shfl_xor(sum, d, 64);
    const float inv = frcp(sum);
    pv.x *= inv; pv.y *= inv; pv.z *= inv; pv.w *= inv;

    *(float4*)&p_lds[wave][lane * 4] = pv;
    const int kbase = lane * 4;
    prob_out[(size_t)(kbase + 0) * 1024 + qb_idx] = pv.x;
    prob_out[(size_t)(kbase + 1) * 1024 + qb_idx] = pv.y;
    prob_out[(size_t)(kbase + 2) * 1024 + qb_idx] = pv.z;
    prob_out[(size_t)(kbase + 3) * 1024 + qb_idx] = pv.w;
    __syncthreads();

    const int h0 = lane * 8;
    float4 accL[4] = {}, accH[4] = {};
    const int kstart = wave * 64;
    #pragma unroll 4
    for (int ki = 0; ki < 64; ++ki) {
        const int k = kstart + ki;
        const float* ckp = &ckey[((size_t)k * 8 + b) * 512 + h0];
        const float4 c0 = *(const float4*)&ckp[0];
        const float4 c1 = *(const float4*)&ckp[4];
        #pragma unroll
        for (int qi = 0; qi < 4; ++qi) {
            const float pq = p_lds[qi][k];
            accL[qi].x = fmaf(pq, c0.x, accL[qi].x);
            accL[qi].y = fmaf(pq, c0.y, accL[qi].y);
            accL[qi].z = fmaf(pq, c0.z, accL[qi].z);
            accL[qi].w = fmaf(pq, c0.w, accL[qi].w);
            accH[qi].x = fmaf(pq, c1.x, accH[qi].x);
            accH[qi].y = fmaf(pq, c1.y, accH[qi].y);
            accH[qi].z = fmaf(pq, c1.z, accH[qi].z);
            accH[qi].w = fmaf(pq, c1.w, accH[qi].w);
        }
    }
    #pragma unroll
    for (int qi = 0; qi < 4; ++qi) {
        *(float4*)&pacc[wave][qi][h0 + 0] = accL[qi];
        *(float4*)&pacc[wave][qi][h0 + 4] = accH[qi];
    }
    __syncthreads();

    const int h2 = t * 2;
    #pragma unroll
    for (int qi = 0; qi < 4; ++qi) {
        float2 r0 = *(const float2*)&pacc[0][qi][h2];
        float2 r1 = *(const float2*)&pacc[1][qi][h2];
        float2 r2 = *(const float2*)&pacc[2][qi][h2];
        float2 r3 = *(const float2*)&pacc[3][qi][h2];
        float2 r;
        r.x = (r0.x + r1.x) + (r2.x + r3.x);
        r.y = (r0.y + r1.y) + (r2.y + r3.y);
        *(float2*)&out_ant[((size_t)(qt * 4 + qi) * 8 + b) * 512 + h2] = r;
    }
}

// ---------------------------------------------------------------------------
extern "C" void kernel_launch(void* const* d_in, const int* in_sizes, int n_in,
                              void* d_out, int out_size, void* d_ws, size_t ws_size,
                              hipStream_t stream)
{
    const float* qry  = (const float*)d_in[0];   // [128][8][512]
    const float* ckey = (const float*)d_in[1];   // [256][8][512]
    const int*   mask = (const int*)d_in[2];     // [256][8]
    const float* W1   = (const float*)d_in[3];   // [1024][512]
    const float* b1   = (const float*)d_in[4];   // [512]
    const float* W2   = (const float*)d_in[5];   // [512]
    const float* b2   = (const float*)d_in[6];   // [1]

    float* out_ant  = (float*)d_out;                      // [128][8][512]
    float* out_prob = (float*)d_out + T_Q * BB * NHID;    // [256][128][8]

    float* ws = (float*)d_ws;
    float* ws_ek = ws;                                        // [2048][512] f32, 4MB
    float* ws_eq = ws + 1048576;                              // [1024][512] f32, 2MB
    unsigned short* bt_hi = (unsigned short*)(ws + 1572864);  // [1024][512] bf16, 1MB
    unsigned short* bt_lo = (unsigned short*)(ws + 1835008);  // 1MB
    float* ws_sc = ws + 2097152;                              // [1024][256] f32, 1MB

    // Cooperative mega-kernel (grid clamped to guaranteed co-residency)
    int maxB = 0;
    (void)hipOccupancyMaxActiveBlocksPerMultiprocessor(&maxB, mega_kernel, 256, 0);
    int nb = (maxB > 0) ? maxB * 256 : 0;
    if (nb > 512) nb = 512;

    hipError_t st = hipErrorUnknown;
    if (nb > 0) {
        void* args[] = {
            (void*)&qry, (void*)&ckey, (void*)&mask, (void*)&W1, (void*)&b1,
            (void*)&W2, (void*)&b2, (void*)&bt_hi, (void*)&bt_lo,
            (void*)&ws_ek, (void*)&ws_eq, (void*)&ws_sc,
            (void*)&out_prob, (void*)&out_ant };
        st = hipLaunchCooperativeKernel(reinterpret_cast<void*>(mega_kernel),
                                        dim3(nb), dim3(256), args, 0, stream);
    }
    if (st != hipSuccess) {
        // Fallback: proven 4-kernel path (R5)
        convert_w1_kernel<<<dim3(128), 256, 0, stream>>>(W1, bt_hi, bt_lo);
        proj_kernel<<<dim3(48, 8), 256, 0, stream>>>(qry, ckey, bt_hi, bt_lo, b1, ws_ek, ws_eq);
        score_kernel<<<dim3(8, 16, 8), 256, 0, stream>>>(ws_ek, ws_eq, W2, b2, mask, ws_sc);
        smav_kernel<<<dim3(32, 8), 256, 0, stream>>>(ws_sc, ckey, out_prob, out_ant);
    }
}

// Round 7
// 126.251 us; speedup vs baseline: 2.1410x; 2.1410x over previous
//
#include <hip/hip_runtime.h>
#include <math.h>

#define NHID 512
#define T_K  256
#define T_Q  128
#define BB   8

// tanh(x) = 1 - 2/(exp2(C*x)+1), C = 2*log2(e)
constexpr float C2L2E = 2.8853900817779268f;
constexpr float L2E   = 1.4426950408889634f;

__device__ __forceinline__ float fexp2(float x) { return __builtin_amdgcn_exp2f(x); }
__device__ __forceinline__ float frcp(float x)  { return __builtin_amdgcn_rcpf(x); }

typedef __attribute__((ext_vector_type(8))) short bf16x8;
typedef __attribute__((ext_vector_type(4))) float f32x4;

__device__ __forceinline__ unsigned short f2bf(float x) {
    unsigned u = __builtin_bit_cast(unsigned, x);
    unsigned r = (u + 0x7FFFu + ((u >> 16) & 1u)) >> 16;
    return (unsigned short)r;
}
__device__ __forceinline__ float bf2f(unsigned short h) {
    unsigned u = ((unsigned)h) << 16;
    return __builtin_bit_cast(float, u);
}

// ---------------------------------------------------------------------------
// Kernel 0: W1 -> BT_hi/lo (split bf16, transposed). 128 blocks. (R5, proven)
// ---------------------------------------------------------------------------
__global__ __launch_bounds__(256) void convert_w1_kernel(
    const float* __restrict__ W1,
    unsigned short* __restrict__ bt_hi, unsigned short* __restrict__ bt_lo)
{
    const int tb = blockIdx.x;   // 0..127
    const int kt = tb & 15;
    const int nt = tb >> 4;
    __shared__ float tile[64][65];
    const int t  = threadIdx.x;
    const int r  = t >> 2;
    const int c0 = (t & 3) * 16;
    const float* src = W1 + (size_t)(kt * 64 + r) * 512 + nt * 64 + c0;
    #pragma unroll
    for (int j = 0; j < 4; ++j) {
        const float4 v = *(const float4*)&src[j * 4];
        tile[r][c0 + j * 4 + 0] = v.x; tile[r][c0 + j * 4 + 1] = v.y;
        tile[r][c0 + j * 4 + 2] = v.z; tile[r][c0 + j * 4 + 3] = v.w;
    }
    __syncthreads();
    const size_t dst = (size_t)((kt >> 3) * 512 + nt * 64 + r) * 512
                     + (size_t)((kt & 7) * 64 + c0);
    #pragma unroll
    for (int j4 = 0; j4 < 4; ++j4) {
        ushort4 h, l;
        #pragma unroll
        for (int e = 0; e < 4; ++e) {
            const float x = tile[c0 + j4 * 4 + e][r];
            const unsigned short hb = f2bf(x);
            ((unsigned short*)&h)[e] = hb;
            ((unsigned short*)&l)[e] = f2bf(x - bf2f(hb));
        }
        *(ushort4*)&bt_hi[dst + j4 * 4] = h;
        *(ushort4*)&bt_lo[dst + j4 * 4] = l;
    }
}

// ---------------------------------------------------------------------------
// Kernel 1: proj GEMM, split-bf16 MFMA; epilogue stores ek=exp2, eq=exp2.
// (R5, proven)
// ---------------------------------------------------------------------------
__global__ __launch_bounds__(256) void proj_kernel(
    const float* __restrict__ qry, const float* __restrict__ ckey,
    const unsigned short* __restrict__ bt_hi, const unsigned short* __restrict__ bt_lo,
    const float* __restrict__ b1,
    float* __restrict__ ek, float* __restrict__ eq)
{
    const int row0 = blockIdx.x * 64;
    const int col0 = blockIdx.y * 64;
    const bool isK = row0 < 2048;
    const int bhalf = isK ? 0 : 512;

    __shared__ __align__(16) unsigned short As_h[64 * 64];
    __shared__ __align__(16) unsigned short As_l[64 * 64];
    __shared__ __align__(16) unsigned short Bs_h[64 * 64];
    __shared__ __align__(16) unsigned short Bs_l[64 * 64];

    const int t    = threadIdx.x;
    const int wave = t >> 6;
    const int lane = t & 63;
    const int wm = (wave & 1) * 32;
    const int wn = (wave >> 1) * 32;

    f32x4 acc[2][2] = {};

    const int sr = t >> 2;
    const int sc = (t & 3) * 16;
    const float* gA = (isK ? ckey + (size_t)(row0 + sr) * 512
                           : qry  + (size_t)(row0 - 2048 + sr) * 512) + sc;
    const unsigned short* gBh = bt_hi + (size_t)(bhalf + col0 + sr) * 512 + sc;
    const unsigned short* gBl = bt_lo + (size_t)(bhalf + col0 + sr) * 512 + sc;
    const int c0c = sc >> 3;
    const int sw0 = ((c0c + 0) ^ (sr & 7)) * 8;
    const int sw1 = ((c0c + 1) ^ (sr & 7)) * 8;

    const int quad = lane >> 4, fr = lane & 15;

    for (int k0 = 0; k0 < 512; k0 += 64) {
        __syncthreads();
        {
            float fa[16];
            *(float4*)&fa[0]  = *(const float4*)&gA[k0 + 0];
            *(float4*)&fa[4]  = *(const float4*)&gA[k0 + 4];
            *(float4*)&fa[8]  = *(const float4*)&gA[k0 + 8];
            *(float4*)&fa[12] = *(const float4*)&gA[k0 + 12];
            union { uint4 v; unsigned short s[8]; } h0, l0, h1, l1;
            #pragma unroll
            for (int e = 0; e < 8; ++e) {
                const unsigned short hb = f2bf(fa[e]);
                h0.s[e] = hb; l0.s[e] = f2bf(fa[e] - bf2f(hb));
            }
            #pragma unroll
            for (int e = 0; e < 8; ++e) {
                const unsigned short hb = f2bf(fa[8 + e]);
                h1.s[e] = hb; l1.s[e] = f2bf(fa[8 + e] - bf2f(hb));
            }
            *(uint4*)&As_h[sr * 64 + sw0] = h0.v; *(uint4*)&As_h[sr * 64 + sw1] = h1.v;
            *(uint4*)&As_l[sr * 64 + sw0] = l0.v; *(uint4*)&As_l[sr * 64 + sw1] = l1.v;
            uint4 v0, v1;
            v0 = *(const uint4*)&gBh[k0];     v1 = *(const uint4*)&gBh[k0 + 8];
            *(uint4*)&Bs_h[sr * 64 + sw0] = v0; *(uint4*)&Bs_h[sr * 64 + sw1] = v1;
            v0 = *(const uint4*)&gBl[k0];     v1 = *(const uint4*)&gBl[k0 + 8];
            *(uint4*)&Bs_l[sr * 64 + sw0] = v0; *(uint4*)&Bs_l[sr * 64 + sw1] = v1;
        }
        __syncthreads();
        #pragma unroll
        for (int ks = 0; ks < 2; ++ks) {
            const int cchunk = ks * 4 + quad;
            bf16x8 afh[2], afl[2], bfh[2], bfl[2];
            #pragma unroll
            for (int mt = 0; mt < 2; ++mt) {
                const int m = wm + mt * 16 + fr;
                afh[mt] = *(const bf16x8*)&As_h[m * 64 + ((cchunk ^ (m & 7)) * 8)];
                afl[mt] = *(const bf16x8*)&As_l[m * 64 + ((cchunk ^ (m & 7)) * 8)];
            }
            #pragma unroll
            for (int nt = 0; nt < 2; ++nt) {
                const int n = wn + nt * 16 + fr;
                bfh[nt] = *(const bf16x8*)&Bs_h[n * 64 + ((cchunk ^ (n & 7)) * 8)];
                bfl[nt] = *(const bf16x8*)&Bs_l[n * 64 + ((cchunk ^ (n & 7)) * 8)];
            }
            #pragma unroll
            for (int mt = 0; mt < 2; ++mt)
                #pragma unroll
                for (int nt = 0; nt < 2; ++nt) {
                    acc[mt][nt] = __builtin_amdgcn_mfma_f32_16x16x32_bf16(afh[mt], bfh[nt], acc[mt][nt], 0, 0, 0);
                    acc[mt][nt] = __builtin_amdgcn_mfma_f32_16x16x32_bf16(afh[mt], bfl[nt], acc[mt][nt], 0, 0, 0);
                    acc[mt][nt] = __builtin_amdgcn_mfma_f32_16x16x32_bf16(afl[mt], bfh[nt], acc[mt][nt], 0, 0, 0);
                }
        }
    }

    #pragma unroll
    for (int nt = 0; nt < 2; ++nt) {
        const int colg = col0 + wn + nt * 16 + fr;
        const float b1v = b1[colg];
        #pragma unroll
        for (int mt = 0; mt < 2; ++mt) {
            #pragma unroll
            for (int i = 0; i < 4; ++i) {
                const int rowg = row0 + wm + mt * 16 + quad * 4 + i;
                const float v = acc[mt][nt][i];
                if (isK) ek[(size_t)rowg * 512 + colg] = fexp2((v + b1v) * C2L2E);
                else     eq[(size_t)(rowg - 2048) * 512 + colg] = fexp2(v * C2L2E);
            }
        }
    }
}

// ---------------------------------------------------------------------------
// Kernel 2 (NEW): fused score + softmax + antvec.
// Grid (64 q-tiles of 2, 8 b) = 512 blocks, 2/CU. Block owns ALL 256 k.
// Score: lane owns k = wave*64+lane; both q are block-uniform -> eq/W2 via
// scalar loads; ek staged [k][h-chunk16] stride 19 (ds_read2, conflict-free);
// no cross-lane reduction (full h-loop in-lane).
// Pair identity: w0/(t0+1)+w1/(t1+1) = (w0*a1 + w1*a0) / (a0*a1), a=t+1.
// Softmax: waves 0,1 (one per q) shuffle-reduce over 256 k in LDS.
// Antvec: wave -> k-quarter, lane -> 8 h; partials in LDS; combine.
// ---------------------------------------------------------------------------
__global__ __launch_bounds__(256) void scoreav_kernel(
    const float* __restrict__ ek, const float* __restrict__ eq,
    const float* __restrict__ W2, const float* __restrict__ b2,
    const int* __restrict__ mask, const float* __restrict__ ckey,
    float* __restrict__ prob_out, float* __restrict__ out_ant)
{
    const int t    = threadIdx.x;
    const int lane = t & 63;
    const int wave = __builtin_amdgcn_readfirstlane(t >> 6);
    const int q0   = blockIdx.x * 2;
    const int b    = blockIdx.y;
    const int myk  = wave * 64 + lane;     // 0..255

    __shared__ float eks[2][256 * 19];     // 38 KB: ek chunk, stride 19
    __shared__ float ps[2][256];           // scores -> probs
    __shared__ float pacc[4][2][512];      // antvec partials, 16 KB

    // base = sum(W2) + b2 (once)
    const float4 wA = *(const float4*)&W2[lane * 4];
    const float4 wB = *(const float4*)&W2[256 + lane * 4];
    float s2 = wA.x + wA.y + wA.z + wA.w + wB.x + wB.y + wB.z + wB.w;
    #pragma unroll
    for (int m = 32; m; m >>= 1) s2 += __shfl_xor(s2, m, 64);
    const float base = s2 + b2[0];

    // block-uniform eq rows -> scalar loads in the hot loop
    const float* __restrict__ eqr0 = eq + (size_t)(q0 * 8 + b) * 512;
    const float* __restrict__ eqr1 = eq + (size_t)((q0 + 1) * 8 + b) * 512;

    // staging: thread t owns k-row t
    const float* __restrict__ ekg = ek + ((size_t)t * 8 + b) * 512;

    // prologue: stage chunk 0
    {
        float fa[16];
        *(float4*)&fa[0]  = *(const float4*)&ekg[0];
        *(float4*)&fa[4]  = *(const float4*)&ekg[4];
        *(float4*)&fa[8]  = *(const float4*)&ekg[8];
        *(float4*)&fa[12] = *(const float4*)&ekg[12];
        #pragma unroll
        for (int j = 0; j < 16; ++j) eks[0][t * 19 + j] = fa[j];
    }
    __syncthreads();

    float racc0 = 0.0f, racc1 = 0.0f;

    for (int chunk = 0; chunk < 32; ++chunk) {
        const int buf = chunk & 1;
        const int hc  = chunk * 16;
        float nf[16];
        if (chunk < 31) {
            *(float4*)&nf[0]  = *(const float4*)&ekg[hc + 16];
            *(float4*)&nf[4]  = *(const float4*)&ekg[hc + 20];
            *(float4*)&nf[8]  = *(const float4*)&ekg[hc + 24];
            *(float4*)&nf[12] = *(const float4*)&ekg[hc + 28];
        }
        #pragma unroll
        for (int s = 0; s < 8; ++s) {
            const float ek0 = eks[buf][myk * 19 + 2 * s + 0];
            const float ek1 = eks[buf][myk * 19 + 2 * s + 1];
            const int h = hc + 2 * s;
            const float w0 = W2[h], w1 = W2[h + 1];         // scalar (SMEM)
            const float e0 = eqr0[h], e1 = eqr0[h + 1];     // scalar
            const float f0 = eqr1[h], f1 = eqr1[h + 1];     // scalar
            {   // q0
                const float t0 = ek0 * e0, t1 = ek1 * e1;
                const float a0 = t0 + 1.0f, a1 = t1 + 1.0f;
                const float den = a0 * a1;
                const float num = fmaf(w0, a1, w1 * a0);
                racc0 = fmaf(num, frcp(den), racc0);
            }
            {   // q1
                const float t0 = ek0 * f0, t1 = ek1 * f1;
                const float a0 = t0 + 1.0f, a1 = t1 + 1.0f;
                const float den = a0 * a1;
                const float num = fmaf(w0, a1, w1 * a0);
                racc1 = fmaf(num, frcp(den), racc1);
            }
        }
        __syncthreads();
        if (chunk < 31) {
            const int nb = buf ^ 1;
            #pragma unroll
            for (int j = 0; j < 16; ++j) eks[nb][t * 19 + j] = nf[j];
        }
        __syncthreads();
    }

    // scores -> LDS
    {
        const int msk = mask[myk * 8 + b];
        float s0 = base - 2.0f * racc0;
        float s1 = base - 2.0f * racc1;
        if (msk) { s0 = -INFINITY; s1 = -INFINITY; }
        ps[0][myk] = s0;
        ps[1][myk] = s1;
    }
    __syncthreads();

    // softmax: waves 0,1 (wave w -> q0+w)
    if (wave < 2) {
        float4 sv = *(const float4*)&ps[wave][lane * 4];
        float m = fmaxf(fmaxf(sv.x, sv.y), fmaxf(sv.z, sv.w));
        #pragma unroll
        for (int d = 32; d; d >>= 1) m = fmaxf(m, __shfl_xor(m, d, 64));
        float4 pv;
        pv.x = fexp2((sv.x - m) * L2E);
        pv.y = fexp2((sv.y - m) * L2E);
        pv.z = fexp2((sv.z - m) * L2E);
        pv.w = fexp2((sv.w - m) * L2E);
        float sum = pv.x + pv.y + pv.z + pv.w;
        #pragma unroll
        for (int d = 32; d; d >>= 1) sum += __shfl_xor(sum, d, 64);
        const float inv = frcp(sum);
        pv.x *= inv; pv.y *= inv; pv.z *= inv; pv.w *= inv;
        *(float4*)&ps[wave][lane * 4] = pv;
        const int qb_idx = (q0 + wave) * 8 + b;
        const int kbase = lane * 4;
        prob_out[(size_t)(kbase + 0) * 1024 + qb_idx] = pv.x;
        prob_out[(size_t)(kbase + 1) * 1024 + qb_idx] = pv.y;
        prob_out[(size_t)(kbase + 2) * 1024 + qb_idx] = pv.z;
        prob_out[(size_t)(kbase + 3) * 1024 + qb_idx] = pv.w;
    }
    __syncthreads();

    // antvec partials: wave -> k-quarter, lane -> 8 h
    {
        const int h0 = lane * 8;
        float4 aL0 = {}, aH0 = {}, aL1 = {}, aH1 = {};
        const int kstart = wave * 64;
        #pragma unroll 4
        for (int ki = 0; ki < 64; ++ki) {
            const int k = kstart + ki;
            const float* ckp = &ckey[((size_t)k * 8 + b) * 512 + h0];
            const float4 c0 = *(const float4*)&ckp[0];
            const float4 c1 = *(const float4*)&ckp[4];
            const float p0 = ps[0][k];
            const float p1 = ps[1][k];
            aL0.x = fmaf(p0, c0.x, aL0.x); aL0.y = fmaf(p0, c0.y, aL0.y);
            aL0.z = fmaf(p0, c0.z, aL0.z); aL0.w = fmaf(p0, c0.w, aL0.w);
            aH0.x = fmaf(p0, c1.x, aH0.x); aH0.y = fmaf(p0, c1.y, aH0.y);
            aH0.z = fmaf(p0, c1.z, aH0.z); aH0.w = fmaf(p0, c1.w, aH0.w);
            aL1.x = fmaf(p1, c0.x, aL1.x); aL1.y = fmaf(p1, c0.y, aL1.y);
            aL1.z = fmaf(p1, c0.z, aL1.z); aL1.w = fmaf(p1, c0.w, aL1.w);
            aH1.x = fmaf(p1, c1.x, aH1.x); aH1.y = fmaf(p1, c1.y, aH1.y);
            aH1.z = fmaf(p1, c1.z, aH1.z); aH1.w = fmaf(p1, c1.w, aH1.w);
        }
        *(float4*)&pacc[wave][0][h0 + 0] = aL0;
        *(float4*)&pacc[wave][0][h0 + 4] = aH0;
        *(float4*)&pacc[wave][1][h0 + 0] = aL1;
        *(float4*)&pacc[wave][1][h0 + 4] = aH1;
    }
    __syncthreads();

    // combine partials: thread t owns h2 = t*2
    {
        const int h2 = t * 2;
        #pragma unroll
        for (int qi = 0; qi < 2; ++qi) {
            float2 r0 = *(const float2*)&pacc[0][qi][h2];
            float2 r1 = *(const float2*)&pacc[1][qi][h2];
            float2 r2 = *(const float2*)&pacc[2][qi][h2];
            float2 r3 = *(const float2*)&pacc[3][qi][h2];
            float2 r;
            r.x = (r0.x + r1.x) + (r2.x + r3.x);
            r.y = (r0.y + r1.y) + (r2.y + r3.y);
            *(float2*)&out_ant[((size_t)(q0 + qi) * 8 + b) * 512 + h2] = r;
        }
    }
}

// ---------------------------------------------------------------------------
extern "C" void kernel_launch(void* const* d_in, const int* in_sizes, int n_in,
                              void* d_out, int out_size, void* d_ws, size_t ws_size,
                              hipStream_t stream)
{
    const float* qry  = (const float*)d_in[0];   // [128][8][512]
    const float* ckey = (const float*)d_in[1];   // [256][8][512]
    const int*   mask = (const int*)d_in[2];     // [256][8]
    const float* W1   = (const float*)d_in[3];   // [1024][512]
    const float* b1   = (const float*)d_in[4];   // [512]
    const float* W2   = (const float*)d_in[5];   // [512]
    const float* b2   = (const float*)d_in[6];   // [1]

    float* out_ant  = (float*)d_out;                      // [128][8][512]
    float* out_prob = (float*)d_out + T_Q * BB * NHID;    // [256][128][8]

    float* ws = (float*)d_ws;
    float* ws_ek = ws;                                        // [2048][512] f32, 4MB
    float* ws_eq = ws + 1048576;                              // [1024][512] f32, 2MB
    unsigned short* bt_hi = (unsigned short*)(ws + 1572864);  // [1024][512] bf16, 1MB
    unsigned short* bt_lo = (unsigned short*)(ws + 1835008);  // 1MB

    convert_w1_kernel<<<dim3(128), 256, 0, stream>>>(W1, bt_hi, bt_lo);
    proj_kernel<<<dim3(48, 8), 256, 0, stream>>>(qry, ckey, bt_hi, bt_lo, b1, ws_ek, ws_eq);
    scoreav_kernel<<<dim3(64, 8), 256, 0, stream>>>(ws_ek, ws_eq, W2, b2, mask, ckey,
                                                    out_prob, out_ant);
}

// Round 8
// 118.562 us; speedup vs baseline: 2.2799x; 1.0649x over previous
//
#include <hip/hip_runtime.h>
#include <math.h>

#define NHID 512
#define T_K  256
#define T_Q  128
#define BB   8

// tanh(x) = 1 - 2/(exp2(C*x)+1), C = 2*log2(e)
constexpr float C2L2E = 2.8853900817779268f;
constexpr float L2E   = 1.4426950408889634f;

__device__ __forceinline__ float fexp2(float x) { return __builtin_amdgcn_exp2f(x); }
__device__ __forceinline__ float frcp(float x)  { return __builtin_amdgcn_rcpf(x); }

typedef __attribute__((ext_vector_type(8))) short bf16x8;
typedef __attribute__((ext_vector_type(4))) float f32x4;

__device__ __forceinline__ unsigned short f2bf(float x) {
    unsigned u = __builtin_bit_cast(unsigned, x);
    unsigned r = (u + 0x7FFFu + ((u >> 16) & 1u)) >> 16;
    return (unsigned short)r;
}
__device__ __forceinline__ float bf2f(unsigned short h) {
    unsigned u = ((unsigned)h) << 16;
    return __builtin_bit_cast(float, u);
}

// ---------------------------------------------------------------------------
// Kernel 0: W1 -> BT_hi/lo (split bf16, transposed). 128 blocks. (proven)
// ---------------------------------------------------------------------------
__global__ __launch_bounds__(256) void convert_w1_kernel(
    const float* __restrict__ W1,
    unsigned short* __restrict__ bt_hi, unsigned short* __restrict__ bt_lo)
{
    const int tb = blockIdx.x;   // 0..127
    const int kt = tb & 15;
    const int nt = tb >> 4;
    __shared__ float tile[64][65];
    const int t  = threadIdx.x;
    const int r  = t >> 2;
    const int c0 = (t & 3) * 16;
    const float* src = W1 + (size_t)(kt * 64 + r) * 512 + nt * 64 + c0;
    #pragma unroll
    for (int j = 0; j < 4; ++j) {
        const float4 v = *(const float4*)&src[j * 4];
        tile[r][c0 + j * 4 + 0] = v.x; tile[r][c0 + j * 4 + 1] = v.y;
        tile[r][c0 + j * 4 + 2] = v.z; tile[r][c0 + j * 4 + 3] = v.w;
    }
    __syncthreads();
    const size_t dst = (size_t)((kt >> 3) * 512 + nt * 64 + r) * 512
                     + (size_t)((kt & 7) * 64 + c0);
    #pragma unroll
    for (int j4 = 0; j4 < 4; ++j4) {
        ushort4 h, l;
        #pragma unroll
        for (int e = 0; e < 4; ++e) {
            const float x = tile[c0 + j4 * 4 + e][r];
            const unsigned short hb = f2bf(x);
            ((unsigned short*)&h)[e] = hb;
            ((unsigned short*)&l)[e] = f2bf(x - bf2f(hb));
        }
        *(ushort4*)&bt_hi[dst + j4 * 4] = h;
        *(ushort4*)&bt_lo[dst + j4 * 4] = l;
    }
}

// ---------------------------------------------------------------------------
// Kernel 1: proj GEMM, split-bf16 MFMA.
// Epilogue: K-side -> ekt[b][h][k] = exp2((acc+b1)*C)  (scattered 4B stores,
// coalesced CONSUMER layout); Q-side -> eq rows = exp2(acc*C) as before.
// ---------------------------------------------------------------------------
__global__ __launch_bounds__(256) void proj_kernel(
    const float* __restrict__ qry, const float* __restrict__ ckey,
    const unsigned short* __restrict__ bt_hi, const unsigned short* __restrict__ bt_lo,
    const float* __restrict__ b1,
    float* __restrict__ ekt, float* __restrict__ eq)
{
    const int row0 = blockIdx.x * 64;
    const int col0 = blockIdx.y * 64;
    const bool isK = row0 < 2048;
    const int bhalf = isK ? 0 : 512;

    __shared__ __align__(16) unsigned short As_h[64 * 64];
    __shared__ __align__(16) unsigned short As_l[64 * 64];
    __shared__ __align__(16) unsigned short Bs_h[64 * 64];
    __shared__ __align__(16) unsigned short Bs_l[64 * 64];

    const int t    = threadIdx.x;
    const int wave = t >> 6;
    const int lane = t & 63;
    const int wm = (wave & 1) * 32;
    const int wn = (wave >> 1) * 32;

    f32x4 acc[2][2] = {};

    const int sr = t >> 2;
    const int sc = (t & 3) * 16;
    const float* gA = (isK ? ckey + (size_t)(row0 + sr) * 512
                           : qry  + (size_t)(row0 - 2048 + sr) * 512) + sc;
    const unsigned short* gBh = bt_hi + (size_t)(bhalf + col0 + sr) * 512 + sc;
    const unsigned short* gBl = bt_lo + (size_t)(bhalf + col0 + sr) * 512 + sc;
    const int c0c = sc >> 3;
    const int sw0 = ((c0c + 0) ^ (sr & 7)) * 8;
    const int sw1 = ((c0c + 1) ^ (sr & 7)) * 8;

    const int quad = lane >> 4, fr = lane & 15;

    for (int k0 = 0; k0 < 512; k0 += 64) {
        __syncthreads();
        {
            float fa[16];
            *(float4*)&fa[0]  = *(const float4*)&gA[k0 + 0];
            *(float4*)&fa[4]  = *(const float4*)&gA[k0 + 4];
            *(float4*)&fa[8]  = *(const float4*)&gA[k0 + 8];
            *(float4*)&fa[12] = *(const float4*)&gA[k0 + 12];
            union { uint4 v; unsigned short s[8]; } h0, l0, h1, l1;
            #pragma unroll
            for (int e = 0; e < 8; ++e) {
                const unsigned short hb = f2bf(fa[e]);
                h0.s[e] = hb; l0.s[e] = f2bf(fa[e] - bf2f(hb));
            }
            #pragma unroll
            for (int e = 0; e < 8; ++e) {
                const unsigned short hb = f2bf(fa[8 + e]);
                h1.s[e] = hb; l1.s[e] = f2bf(fa[8 + e] - bf2f(hb));
            }
            *(uint4*)&As_h[sr * 64 + sw0] = h0.v; *(uint4*)&As_h[sr * 64 + sw1] = h1.v;
            *(uint4*)&As_l[sr * 64 + sw0] = l0.v; *(uint4*)&As_l[sr * 64 + sw1] = l1.v;
            uint4 v0, v1;
            v0 = *(const uint4*)&gBh[k0];     v1 = *(const uint4*)&gBh[k0 + 8];
            *(uint4*)&Bs_h[sr * 64 + sw0] = v0; *(uint4*)&Bs_h[sr * 64 + sw1] = v1;
            v0 = *(const uint4*)&gBl[k0];     v1 = *(const uint4*)&gBl[k0 + 8];
            *(uint4*)&Bs_l[sr * 64 + sw0] = v0; *(uint4*)&Bs_l[sr * 64 + sw1] = v1;
        }
        __syncthreads();
        #pragma unroll
        for (int ks = 0; ks < 2; ++ks) {
            const int cchunk = ks * 4 + quad;
            bf16x8 afh[2], afl[2], bfh[2], bfl[2];
            #pragma unroll
            for (int mt = 0; mt < 2; ++mt) {
                const int m = wm + mt * 16 + fr;
                afh[mt] = *(const bf16x8*)&As_h[m * 64 + ((cchunk ^ (m & 7)) * 8)];
                afl[mt] = *(const bf16x8*)&As_l[m * 64 + ((cchunk ^ (m & 7)) * 8)];
            }
            #pragma unroll
            for (int nt = 0; nt < 2; ++nt) {
                const int n = wn + nt * 16 + fr;
                bfh[nt] = *(const bf16x8*)&Bs_h[n * 64 + ((cchunk ^ (n & 7)) * 8)];
                bfl[nt] = *(const bf16x8*)&Bs_l[n * 64 + ((cchunk ^ (n & 7)) * 8)];
            }
            #pragma unroll
            for (int mt = 0; mt < 2; ++mt)
                #pragma unroll
                for (int nt = 0; nt < 2; ++nt) {
                    acc[mt][nt] = __builtin_amdgcn_mfma_f32_16x16x32_bf16(afh[mt], bfh[nt], acc[mt][nt], 0, 0, 0);
                    acc[mt][nt] = __builtin_amdgcn_mfma_f32_16x16x32_bf16(afh[mt], bfl[nt], acc[mt][nt], 0, 0, 0);
                    acc[mt][nt] = __builtin_amdgcn_mfma_f32_16x16x32_bf16(afl[mt], bfh[nt], acc[mt][nt], 0, 0, 0);
                }
        }
    }

    #pragma unroll
    for (int nt = 0; nt < 2; ++nt) {
        const int colg = col0 + wn + nt * 16 + fr;   // = h
        const float b1v = b1[colg];
        #pragma unroll
        for (int mt = 0; mt < 2; ++mt) {
            #pragma unroll
            for (int i = 0; i < 4; ++i) {
                const int rowg = row0 + wm + mt * 16 + quad * 4 + i;
                const float v = acc[mt][nt][i];
                if (isK) {
                    const int kidx = rowg >> 3;      // k
                    const int bb   = rowg & 7;       // b
                    ekt[((size_t)bb * 512 + colg) * 256 + kidx] = fexp2((v + b1v) * C2L2E);
                } else {
                    eq[(size_t)(rowg - 2048) * 512 + colg] = fexp2(v * C2L2E);
                }
            }
        }
    }
}

// ---------------------------------------------------------------------------
// Kernel 2: fused score + softmax + antvec, NO hot-loop barriers / LDS stage.
// Grid (64 q-tiles of 2, 8 b) = 512 blocks. Thread t owns k = t.
// ekt[b][h][k]: coalesced global dword per h. eq rows + W2 staged once in
// LDS (uniform broadcast reads). Pair identity per (h-pair, q):
//   w0/(t0+1)+w1/(t1+1) = (w0*a1 + w1*a0) * rcp(a0*a1), a = t+1, t = ek*eq.
// Then softmax (waves 0,1) and antvec partials (wave->k-quarter) as R7.
// ---------------------------------------------------------------------------
__global__ __launch_bounds__(256) void scoreav_kernel(
    const float* __restrict__ ekt, const float* __restrict__ eq,
    const float* __restrict__ W2, const float* __restrict__ b2,
    const int* __restrict__ mask, const float* __restrict__ ckey,
    float* __restrict__ prob_out, float* __restrict__ out_ant)
{
    const int t    = threadIdx.x;
    const int lane = t & 63;
    const int wave = __builtin_amdgcn_readfirstlane(t >> 6);
    const int q0   = blockIdx.x * 2;
    const int b    = blockIdx.y;

    __shared__ float eq0s[512], eq1s[512], w2s[512];   // 6 KB
    __shared__ float ps[2][256];                       // 2 KB
    __shared__ float pacc[4][2][512];                  // 16 KB

    // stage block-uniform vectors (2 floats/thread each)
    {
        const float2 v0 = *(const float2*)&eq[((size_t)q0 * 8 + b) * 512 + t * 2];
        const float2 v1 = *(const float2*)&eq[((size_t)(q0 + 1) * 8 + b) * 512 + t * 2];
        const float2 w  = *(const float2*)&W2[t * 2];
        *(float2*)&eq0s[t * 2] = v0;
        *(float2*)&eq1s[t * 2] = v1;
        *(float2*)&w2s[t * 2]  = w;
    }

    // base = sum(W2) + b2
    const float4 wA = *(const float4*)&W2[lane * 4];
    const float4 wB = *(const float4*)&W2[256 + lane * 4];
    float s2 = wA.x + wA.y + wA.z + wA.w + wB.x + wB.y + wB.z + wB.w;
    #pragma unroll
    for (int m = 32; m; m >>= 1) s2 += __shfl_xor(s2, m, 64);
    const float base = s2 + b2[0];
    __syncthreads();

    // ---- score: thread t owns k = t; stream ekt coalesced ----
    const float* __restrict__ ekb = ekt + (size_t)b * 512 * 256 + t;
    float racc0 = 0.0f, racc1 = 0.0f;

    #pragma unroll 8
    for (int hp = 0; hp < 256; ++hp) {
        const int h = hp * 2;
        const float ek0 = ekb[(size_t)h * 256];
        const float ek1 = ekb[(size_t)(h + 1) * 256];
        const float w0 = w2s[h], w1 = w2s[h + 1];
        const float e0 = eq0s[h], e1 = eq0s[h + 1];
        const float f0 = eq1s[h], f1 = eq1s[h + 1];
        {   // q0
            const float t0 = ek0 * e0, t1 = ek1 * e1;
            const float a0 = t0 + 1.0f, a1 = t1 + 1.0f;
            const float num = fmaf(w0, a1, w1 * a0);
            racc0 = fmaf(num, frcp(a0 * a1), racc0);
        }
        {   // q1
            const float t0 = ek0 * f0, t1 = ek1 * f1;
            const float a0 = t0 + 1.0f, a1 = t1 + 1.0f;
            const float num = fmaf(w0, a1, w1 * a0);
            racc1 = fmaf(num, frcp(a0 * a1), racc1);
        }
    }

    // scores -> LDS
    {
        const int msk = mask[t * 8 + b];
        float s0 = base - 2.0f * racc0;
        float s1 = base - 2.0f * racc1;
        if (msk) { s0 = -INFINITY; s1 = -INFINITY; }
        ps[0][t] = s0;
        ps[1][t] = s1;
    }
    __syncthreads();

    // ---- softmax: waves 0,1 (wave w -> q0+w) ----
    if (wave < 2) {
        float4 sv = *(const float4*)&ps[wave][lane * 4];
        float m = fmaxf(fmaxf(sv.x, sv.y), fmaxf(sv.z, sv.w));
        #pragma unroll
        for (int d = 32; d; d >>= 1) m = fmaxf(m, __shfl_xor(m, d, 64));
        float4 pv;
        pv.x = fexp2((sv.x - m) * L2E);
        pv.y = fexp2((sv.y - m) * L2E);
        pv.z = fexp2((sv.z - m) * L2E);
        pv.w = fexp2((sv.w - m) * L2E);
        float sum = pv.x + pv.y + pv.z + pv.w;
        #pragma unroll
        for (int d = 32; d; d >>= 1) sum += __shfl_xor(sum, d, 64);
        const float inv = frcp(sum);
        pv.x *= inv; pv.y *= inv; pv.z *= inv; pv.w *= inv;
        *(float4*)&ps[wave][lane * 4] = pv;
        const int qb_idx = (q0 + wave) * 8 + b;
        const int kbase = lane * 4;
        prob_out[(size_t)(kbase + 0) * 1024 + qb_idx] = pv.x;
        prob_out[(size_t)(kbase + 1) * 1024 + qb_idx] = pv.y;
        prob_out[(size_t)(kbase + 2) * 1024 + qb_idx] = pv.z;
        prob_out[(size_t)(kbase + 3) * 1024 + qb_idx] = pv.w;
    }
    __syncthreads();

    // ---- antvec partials: wave -> k-quarter, lane -> 8 h ----
    {
        const int h0 = lane * 8;
        float4 aL0 = {}, aH0 = {}, aL1 = {}, aH1 = {};
        const int kstart = wave * 64;
        #pragma unroll 4
        for (int ki = 0; ki < 64; ++ki) {
            const int k = kstart + ki;
            const float* ckp = &ckey[((size_t)k * 8 + b) * 512 + h0];
            const float4 c0 = *(const float4*)&ckp[0];
            const float4 c1 = *(const float4*)&ckp[4];
            const float p0 = ps[0][k];
            const float p1 = ps[1][k];
            aL0.x = fmaf(p0, c0.x, aL0.x); aL0.y = fmaf(p0, c0.y, aL0.y);
            aL0.z = fmaf(p0, c0.z, aL0.z); aL0.w = fmaf(p0, c0.w, aL0.w);
            aH0.x = fmaf(p0, c1.x, aH0.x); aH0.y = fmaf(p0, c1.y, aH0.y);
            aH0.z = fmaf(p0, c1.z, aH0.z); aH0.w = fmaf(p0, c1.w, aH0.w);
            aL1.x = fmaf(p1, c0.x, aL1.x); aL1.y = fmaf(p1, c0.y, aL1.y);
            aL1.z = fmaf(p1, c0.z, aL1.z); aL1.w = fmaf(p1, c0.w, aL1.w);
            aH1.x = fmaf(p1, c1.x, aH1.x); aH1.y = fmaf(p1, c1.y, aH1.y);
            aH1.z = fmaf(p1, c1.z, aH1.z); aH1.w = fmaf(p1, c1.w, aH1.w);
        }
        *(float4*)&pacc[wave][0][h0 + 0] = aL0;
        *(float4*)&pacc[wave][0][h0 + 4] = aH0;
        *(float4*)&pacc[wave][1][h0 + 0] = aL1;
        *(float4*)&pacc[wave][1][h0 + 4] = aH1;
    }
    __syncthreads();

    // ---- combine: thread t owns h2 = t*2 ----
    {
        const int h2 = t * 2;
        #pragma unroll
        for (int qi = 0; qi < 2; ++qi) {
            float2 r0 = *(const float2*)&pacc[0][qi][h2];
            float2 r1 = *(const float2*)&pacc[1][qi][h2];
            float2 r2 = *(const float2*)&pacc[2][qi][h2];
            float2 r3 = *(const float2*)&pacc[3][qi][h2];
            float2 r;
            r.x = (r0.x + r1.x) + (r2.x + r3.x);
            r.y = (r0.y + r1.y) + (r2.y + r3.y);
            *(float2*)&out_ant[((size_t)(q0 + qi) * 8 + b) * 512 + h2] = r;
        }
    }
}

// ---------------------------------------------------------------------------
extern "C" void kernel_launch(void* const* d_in, const int* in_sizes, int n_in,
                              void* d_out, int out_size, void* d_ws, size_t ws_size,
                              hipStream_t stream)
{
    const float* qry  = (const float*)d_in[0];   // [128][8][512]
    const float* ckey = (const float*)d_in[1];   // [256][8][512]
    const int*   mask = (const int*)d_in[2];     // [256][8]
    const float* W1   = (const float*)d_in[3];   // [1024][512]
    const float* b1   = (const float*)d_in[4];   // [512]
    const float* W2   = (const float*)d_in[5];   // [512]
    const float* b2   = (const float*)d_in[6];   // [1]

    float* out_ant  = (float*)d_out;                      // [128][8][512]
    float* out_prob = (float*)d_out + T_Q * BB * NHID;    // [256][128][8]

    float* ws = (float*)d_ws;
    float* ws_ekt = ws;                                       // [8][512][256] f32, 4MB
    float* ws_eq  = ws + 1048576;                             // [1024][512] f32, 2MB
    unsigned short* bt_hi = (unsigned short*)(ws + 1572864);  // [1024][512] bf16, 1MB
    unsigned short* bt_lo = (unsigned short*)(ws + 1835008);  // 1MB

    convert_w1_kernel<<<dim3(128), 256, 0, stream>>>(W1, bt_hi, bt_lo);
    proj_kernel<<<dim3(48, 8), 256, 0, stream>>>(qry, ckey, bt_hi, bt_lo, b1, ws_ekt, ws_eq);
    scoreav_kernel<<<dim3(64, 8), 256, 0, stream>>>(ws_ekt, ws_eq, W2, b2, mask, ckey,
                                                    out_prob, out_ant);
}